// Round 15
// baseline (103.817 us; speedup 1.0000x reference)
//
#include <hip/hip_runtime.h>
#include <stdint.h>

// Problem constants: x (4, 8192, 512) f32, A/B (512, 64), h0 scalar.
#define NBATCH 4
#define LSEQ   8192
#define CH     512
#define ORDER  64
#define KTAP   256           // validated R3-R14: tail < 1e-5, threshold 5.86e-3
#define NW     9             // windows T0_w = 32w+15 cover t in [0,256) once/row

typedef _Float16 half8 __attribute__((ext_vector_type(8)));
typedef __fp16   fp16x2 __attribute__((ext_vector_type(2)));
typedef float    f32x4 __attribute__((ext_vector_type(4)));

#define AFRAG_HALFS  ((size_t)CH * NW * 64 * 8)        // 4.7 MB
#define WS_NEED      (AFRAG_HALFS * 2)

// ---- fir geometry (tile = 16 ch x 512 n, frag math proven R12-R14) ---------
#define XROWB 1584           // 792 halves/row; b128 reads conflict-free
#define SMEMB (16 * XROWB)   // 25344 B per buffer
#define PAIRS 392            // row-pairs staged/tile: rows n0-271 .. n0+512
#define TPB   4              // tiles per block (4 x 512 = 2048 n)

__device__ __forceinline__ uint32_t pkrtz(float lo, float hi) {
    fp16x2 v = __builtin_amdgcn_cvt_pkrtz(lo, hi);
    return __builtin_bit_cast(uint32_t, v);
}

// ---------------------------------------------------------------------------
// Kernel 1: IIR impulse response -> per-channel MFMA A-fragments (proven
// R7-R14). A_w[i][k] = Kx[32w+15+i-k], lane l: i=l&15, k=8*(l>>4)+e; h0
// folded into Kx[0]; Kx zero outside [0,KTAP). 4 channels/block.
// ---------------------------------------------------------------------------
__global__ __launch_bounds__(256) void rtf_afrag(const float* __restrict__ A,
                                                 const float* __restrict__ B,
                                                 const float* __restrict__ h0,
                                                 _Float16* __restrict__ afr) {
    __shared__ float Ksh[4][KTAP];
    const int wv = threadIdx.x >> 6, lane = threadIdx.x & 63;
    const int c  = blockIdx.x * 4 + wv;
    const float a  = A[c * ORDER + lane];
    const float bc = B[c * ORDER + lane];
    const float h0v = h0[0];
    float s = 0.0f;
    for (int t = 0; t < KTAP; ++t) {
        const float s1 = __shfl(s, 0);
        const float bt = (t < ORDER) ? __shfl(bc, t) : 0.0f;
        const float y  = bt + s1;
        float su = __shfl_down(s, 1);
        if (lane == ORDER - 1) su = 0.0f;
        s = su - a * y;
        if (lane == 0) Ksh[wv][t] = (t == 0) ? (y + h0v) : y;
    }
    __syncthreads();
    const int i = lane & 15, g = lane >> 4;
    for (int w = 0; w < NW; ++w) {
        half8 hv;
#pragma unroll
        for (int e = 0; e < 8; ++e) {
            const int t = 32 * w + 15 + i - 8 * g - e;
            hv[e] = (_Float16)((t >= 0 && t < KTAP) ? Ksh[wv][t] : 0.0f);
        }
        *reinterpret_cast<half8*>(afr + ((size_t)(c * NW + w) * 64 + lane) * 8) = hv;
    }
}

// ---------------------------------------------------------------------------
// Kernel 2: producer/consumer banded-Toeplitz MFMA FIR + gelu.
// 512 blocks (2/CU by LDS), 512 threads: waves 0-3 PRODUCE (global->pack->
// LDS, double-buffered xs; their vmcnt stall is absorbed while consumer
// waves run on the same CU), waves 4-7 CONSUME (ds_read_b128 + MFMA + gelu).
// Block covers 16 ch x 2048 n (4 tiles of 512), consecutive tiles -> halo
// L2-hot. All barriers unconditional (4/tile); stores use all 8 waves.
// ---------------------------------------------------------------------------
__global__ __launch_bounds__(512, 4) void fir_pc(const float* __restrict__ x,
                                                 const _Float16* __restrict__ afr,
                                                 float* __restrict__ out) {
    __shared__ __align__(16) char  xs2[2 * SMEMB];   // 50.7 KB double buffer
    __shared__ float lout[16][260];                  // 16.6 KB
    const int gid     = blockIdx.x;
    const int logical = (gid & 7) * 64 + (gid >> 3); // bijective (512%8==0)
    const int chgrp   = logical >> 4;                // 0..31, 4 per XCD
    const int bb      = (logical >> 2) & 3;
    const int qt      = logical & 3;
    const int nbase   = qt * (TPB * 512);
    const int c0      = chgrp * 16;

    const int wid      = threadIdx.x >> 6;
    const bool producer = (wid < 4);

    // producer indexing (threads 0..255)
    const int q  = threadIdx.x & 3;
    const int pr = (threadIdx.x & 255) >> 2;         // 0..63
    const float* xsrc = x + (size_t)bb * LSEQ * CH + c0 + q * 4;

#define STAGE(N0K, BUF)                                                       \
    {                                                                         \
        f32x4 L0[7], L1[7];                                                   \
        _Pragma("unroll")                                                     \
        for (int i = 0; i < 7; ++i) {                                         \
            const int p = pr + 64 * i;                                        \
            f32x4 z = {0.f, 0.f, 0.f, 0.f};                                   \
            L0[i] = z; L1[i] = z;                                             \
            if (p < PAIRS) {                                                  \
                const int r0 = (N0K) - 271 + 2 * p;                           \
                if ((unsigned)r0 < LSEQ)                                      \
                    L0[i] = *reinterpret_cast<const f32x4*>(xsrc + (size_t)r0 * CH); \
                if ((unsigned)(r0 + 1) < LSEQ)                                \
                    L1[i] = *reinterpret_cast<const f32x4*>(xsrc + (size_t)(r0 + 1) * CH); \
            }                                                                 \
        }                                                                     \
        _Pragma("unroll")                                                     \
        for (int i = 0; i < 7; ++i) {                                         \
            const int p = pr + 64 * i;                                        \
            if (p < PAIRS) {                                                  \
                char* wb = (BUF) + (size_t)(4 * q) * XROWB + 4 * p;           \
                *reinterpret_cast<uint32_t*>(wb + 0 * XROWB) = pkrtz(L0[i][0], L1[i][0]); \
                *reinterpret_cast<uint32_t*>(wb + 1 * XROWB) = pkrtz(L0[i][1], L1[i][1]); \
                *reinterpret_cast<uint32_t*>(wb + 2 * XROWB) = pkrtz(L0[i][2], L1[i][2]); \
                *reinterpret_cast<uint32_t*>(wb + 3 * XROWB) = pkrtz(L0[i][3], L1[i][3]); \
            }                                                                 \
        }                                                                     \
    }

    // consumer indexing (threads 256..511)
    const int cid  = threadIdx.x & 255;
    const int cw   = cid >> 6;                       // 0..3
    const int lane = cid & 63;
    const int j = lane & 15, g = lane >> 4;
    const int c0w = c0 + cw * 4;
    const _Float16* af = afr + (size_t)lane * 8;

    // store indexing (all 512 threads)
    const int scq = threadIdx.x & 3;
    const int snr = threadIdx.x >> 2;                // 0..127

    // ---- prologue: producers stage tile 0 into buf 0 ----
    if (producer) STAGE(nbase, xs2);
    __syncthreads();

#pragma unroll 1
    for (int k = 0; k < TPB; ++k) {
        const int n0 = nbase + 512 * k;
        char* bufc = xs2 + (size_t)(k & 1) * SMEMB;
        char* bufn = xs2 + (size_t)((k + 1) & 1) * SMEMB;

        f32x4 acc[2][4];
        if (producer) {
            // ---- phase A (producer): stage tile k+1 into the other buffer ----
            if (k < TPB - 1) STAGE(n0 + 512, bufn);
        } else {
            // ---- phase A (consumer): 9 windows x 2 subtiles x 4 ch ----
#pragma unroll
            for (int ti = 0; ti < 2; ++ti)
#pragma unroll
                for (int qq = 0; qq < 4; ++qq) acc[ti][qq] = (f32x4){0.f, 0.f, 0.f, 0.f};
            half8 a_cur[4], a_nxt[4];
#pragma unroll
            for (int qq = 0; qq < 4; ++qq)
                a_cur[qq] = *reinterpret_cast<const half8*>(af + (size_t)((c0w + qq) * NW + 0) * 512);
#pragma unroll
            for (int w = 0; w < NW; ++w) {
                if (w < NW - 1) {
#pragma unroll
                    for (int qq = 0; qq < 4; ++qq)
                        a_nxt[qq] = *reinterpret_cast<const half8*>(af + (size_t)((c0w + qq) * NW + (w + 1)) * 512);
                }
                const int idx0 = 16 * j + 8 * g - 32 * w + 256;   // %8==0, b128-aligned
#pragma unroll
                for (int ti = 0; ti < 2; ++ti) {
#pragma unroll
                    for (int qq = 0; qq < 4; ++qq) {
                        const half8 bv = *reinterpret_cast<const half8*>(
                            bufc + (size_t)(cw * 4 + qq) * XROWB + 2 * (idx0 + 256 * ti));
                        acc[ti][qq] = __builtin_amdgcn_mfma_f32_16x16x32_f16(a_cur[qq], bv, acc[ti][qq], 0, 0, 0);
                    }
                }
#pragma unroll
                for (int qq = 0; qq < 4; ++qq) a_cur[qq] = a_nxt[qq];
            }
            // gelu subtile 0 -> lout
#pragma unroll
            for (int qq = 0; qq < 4; ++qq) {
                f32x4 o;
#pragma unroll
                for (int r = 0; r < 4; ++r) {
                    const float y  = acc[0][qq][r];
                    const float wv = fmaf(y * y, 0.14270963f, 1.5957691f);
                    const float e  = __expf(y * wv);
                    o[r] = y - y * __builtin_amdgcn_rcpf(e + 1.0f);
                }
                *reinterpret_cast<f32x4*>(&lout[cw * 4 + qq][16 * j + 4 * g]) = o;
            }
        }
        __syncthreads();                             // B1: lout ti0 + buf[nxt] ready

        // ---- store subtile 0 (all 512 threads) ----
        {
            float* obp = out + ((size_t)bb * LSEQ + n0) * CH + c0 + 4 * scq;
#pragma unroll
            for (int it = 0; it < 2; ++it) {
                const int n = snr + 128 * it;
                f32x4 o;
                o[0] = lout[4 * scq + 0][n];
                o[1] = lout[4 * scq + 1][n];
                o[2] = lout[4 * scq + 2][n];
                o[3] = lout[4 * scq + 3][n];
                *reinterpret_cast<f32x4*>(obp + (size_t)n * CH) = o;
            }
        }
        __syncthreads();                             // B2: lout free

        if (!producer) {
            // gelu subtile 1 -> lout
#pragma unroll
            for (int qq = 0; qq < 4; ++qq) {
                f32x4 o;
#pragma unroll
                for (int r = 0; r < 4; ++r) {
                    const float y  = acc[1][qq][r];
                    const float wv = fmaf(y * y, 0.14270963f, 1.5957691f);
                    const float e  = __expf(y * wv);
                    o[r] = y - y * __builtin_amdgcn_rcpf(e + 1.0f);
                }
                *reinterpret_cast<f32x4*>(&lout[cw * 4 + qq][16 * j + 4 * g]) = o;
            }
        }
        __syncthreads();                             // B3: lout ti1 ready

        // ---- store subtile 1 (all 512 threads) ----
        {
            float* obp = out + ((size_t)bb * LSEQ + n0 + 256) * CH + c0 + 4 * scq;
#pragma unroll
            for (int it = 0; it < 2; ++it) {
                const int n = snr + 128 * it;
                f32x4 o;
                o[0] = lout[4 * scq + 0][n];
                o[1] = lout[4 * scq + 1][n];
                o[2] = lout[4 * scq + 2][n];
                o[3] = lout[4 * scq + 3][n];
                *reinterpret_cast<f32x4*>(obp + (size_t)n * CH) = o;
            }
        }
        __syncthreads();                             // B4: tile done; buf swap safe
    }
#undef STAGE
}

// ======================== FALLBACK (R5, proven 138us) =======================
#define RINGF 32
#define CPBF  256
__global__ __launch_bounds__(ORDER) void rtf_impulse_fb(const float* __restrict__ A,
                                                        const float* __restrict__ B,
                                                        const float* __restrict__ h0,
                                                        float* __restrict__ kt4) {
    const int c = blockIdx.x, lane = threadIdx.x;
    const float a = A[c * ORDER + lane], bc = B[c * ORDER + lane], h0v = h0[0];
    float s = 0.0f;
    for (int t = 0; t < KTAP; ++t) {
        const float s1 = __shfl(s, 0);
        const float bt = (t < ORDER) ? __shfl(bc, t) : 0.0f;
        const float y  = bt + s1;
        float su = __shfl_down(s, 1);
        if (lane == ORDER - 1) su = 0.0f;
        s = su - a * y;
        if (lane == 0) kt4[((size_t)(t >> 2) * CH + c) * 4 + (t & 3)] = (t == 0) ? (y + h0v) : y;
    }
}
__global__ __launch_bounds__(CPBF) void fir_gelu_fb(const float* __restrict__ x,
                                                    const float* __restrict__ kt4,
                                                    float* __restrict__ out) {
    const int h = blockIdx.x;
    const int logical = ((h & 7) << 8) | (h >> 3);
    const int tile = logical & 255, sl = logical >> 8;
    const int cb = sl & 1, b = sl >> 1;
    const int c = cb * CPBF + threadIdx.x;
    const int n0 = tile * RINGF;
    const float* xb = x + (size_t)b * LSEQ * CH + c;
    const float4* kt4v = (const float4*)kt4;
    float acc[RINGF]; float ring[RINGF]; float px[2][8]; float kbuf[2][8];
#pragma unroll
    for (int r = 0; r < RINGF; ++r) acc[r] = 0.0f;
#pragma unroll
    for (int i = 0; i < RINGF; ++i) ring[i] = xb[(size_t)(n0 + i) * CH];
    {
        const float4 ka = kt4v[(size_t)0 * CH + c];
        const float4 kb = kt4v[(size_t)1 * CH + c];
        kbuf[0][0] = ka.x; kbuf[0][1] = ka.y; kbuf[0][2] = ka.z; kbuf[0][3] = ka.w;
        kbuf[0][4] = kb.x; kbuf[0][5] = kb.y; kbuf[0][6] = kb.z; kbuf[0][7] = kb.w;
#pragma unroll
        for (int g2 = 0; g2 < 8; ++g2) {
            const int m = n0 - 1 - g2;
            px[0][g2] = (m >= 0) ? xb[(size_t)m * CH] : 0.0f;
        }
    }
    for (int tb = 0; tb < KTAP; tb += RINGF) {
#pragma unroll
        for (int qq = 0; qq < 4; ++qq) {
            const int cur = qq & 1, nxt = cur ^ 1;
            const int tn = tb + 8 * (qq + 1);
            if (tn < KTAP) {
                const float4 ka = kt4v[(size_t)(tn >> 2) * CH + c];
                const float4 kb = kt4v[(size_t)((tn >> 2) + 1) * CH + c];
                kbuf[nxt][0] = ka.x; kbuf[nxt][1] = ka.y; kbuf[nxt][2] = ka.z; kbuf[nxt][3] = ka.w;
                kbuf[nxt][4] = kb.x; kbuf[nxt][5] = kb.y; kbuf[nxt][6] = kb.z; kbuf[nxt][7] = kb.w;
#pragma unroll
                for (int g2 = 0; g2 < 8; ++g2) {
                    const int m = n0 - tn - 1 - g2;
                    px[nxt][g2] = (m >= 0) ? xb[(size_t)m * CH] : 0.0f;
                }
            }
#pragma unroll
            for (int g2 = 0; g2 < 8; ++g2) {
                const int tq = 8 * qq + g2;
                const float kv = kbuf[cur][g2];
#pragma unroll
                for (int r = 0; r < RINGF; ++r)
                    acc[r] = fmaf(kv, ring[(r - tq) & (RINGF - 1)], acc[r]);
                ring[(RINGF - 1 - tq) & (RINGF - 1)] = px[cur][g2];
            }
        }
    }
    float* ob = out + ((size_t)b * LSEQ + n0) * CH + c;
#pragma unroll
    for (int r = 0; r < RINGF; ++r) {
        const float y = acc[r];
        const float wv = fmaf(y * y, 0.14270963f, 1.5957691f);
        const float e = __expf(y * wv);
        ob[(size_t)r * CH] = y - y * __builtin_amdgcn_rcpf(e + 1.0f);
    }
}

extern "C" void kernel_launch(void* const* d_in, const int* in_sizes, int n_in,
                              void* d_out, int out_size, void* d_ws, size_t ws_size,
                              hipStream_t stream) {
    const float* x  = (const float*)d_in[0];
    const float* A  = (const float*)d_in[1];
    const float* B  = (const float*)d_in[2];
    const float* h0 = (const float*)d_in[3];
    float* out = (float*)d_out;

    if (ws_size >= WS_NEED) {
        _Float16* afr = (_Float16*)d_ws;
        rtf_afrag<<<dim3(CH / 4), dim3(256), 0, stream>>>(A, B, h0, afr);
        fir_pc<<<dim3(512), dim3(512), 0, stream>>>(x, afr, out);
    } else {
        float* kt4 = (float*)d_ws;  // 512 KB
        rtf_impulse_fb<<<dim3(CH), dim3(ORDER), 0, stream>>>(A, B, h0, kt4);
        fir_gelu_fb<<<dim3((LSEQ / RINGF) * (CH / CPBF) * NBATCH), dim3(CPBF), 0, stream>>>(x, kt4, out);
    }
}

// Round 16
// 60.165 us; speedup vs baseline: 1.7255x; 1.7255x over previous
//
#include <hip/hip_runtime.h>
#include <stdint.h>

// Problem constants: x (4, 8192, 512) f32, A/B (512, 64), h0 scalar.
#define NBATCH 4
#define LSEQ   8192
#define CH     512
#define ORDER  64
#define KTAP   256           // validated R3-R15: tail < 1e-5, threshold 5.86e-3

typedef _Float16 half8 __attribute__((ext_vector_type(8)));
typedef _Float16 half4 __attribute__((ext_vector_type(4)));
typedef float    f32x4 __attribute__((ext_vector_type(4)));

// Transposed/padded x geometry: column p = PAD0 + row, zeros outside [0,8192).
#define PADP  8512
#define PAD0  279
#define NW    9              // windows T0_w = 32w+15 cover t in [0,256) once/row

#define AFRAG_HALFS  ((size_t)CH * NW * 64 * 8)        // 4.7 MB
#define XT_HALFS     ((size_t)CH * NBATCH * PADP)      // 34.9 MB
#define WS_NEED      ((AFRAG_HALFS + XT_HALFS) * 2)

#define NAPREP 128                       // afrag blocks (4 ch each)
#define NXPOSE (133 * 8 * NBATCH)        // xpose blocks (PADP/64 x CH/64 x B)

// fir LDS: xs[16 ch][1312 halves] (2624 B row stride), lout[16][260 f32]
// ALIASED onto xs (xs dead after MFMA loop; epilogue barrier orders it).
#define XROWB 2624
#define SMEMB (16 * XROWB)   // 41984 B -> 3 blocks/CU (was 58.9KB -> 2)
#define LOWB  1040

// ---------------------------------------------------------------------------
// Kernel 1 (fused prep, PROVEN R8): blocks [0,128) build per-channel MFMA
// A-fragments (IIR impulse response, 4 ch/block); blocks [128,128+4256)
// transpose x to xT[c*4+b][p] f16 zero-padded (64x64 LDS tile).
// ---------------------------------------------------------------------------
__global__ __launch_bounds__(256) void prep(const float* __restrict__ A,
                                            const float* __restrict__ B,
                                            const float* __restrict__ h0,
                                            const float* __restrict__ x,
                                            _Float16* __restrict__ afr,
                                            _Float16* __restrict__ xT) {
    __shared__ float    Ksh[4][KTAP];
    __shared__ _Float16 tile[64][74];
    const int bid = blockIdx.x;
    if (bid < NAPREP) {
        // A_w[i][k] = Kx[32w+15+i-k], lane l: i=l&15, k=8*(l>>4)+e; h0 folded
        // into Kx[0]; Kx zero outside [0,KTAP).
        const int wv = threadIdx.x >> 6, lane = threadIdx.x & 63;
        const int c  = bid * 4 + wv;
        const float a  = A[c * ORDER + lane];
        const float bc = B[c * ORDER + lane];
        const float h0v = h0[0];
        float s = 0.0f;
        for (int t = 0; t < KTAP; ++t) {
            const float s1 = __shfl(s, 0);
            const float bt = (t < ORDER) ? __shfl(bc, t) : 0.0f;
            const float y  = bt + s1;
            float su = __shfl_down(s, 1);
            if (lane == ORDER - 1) su = 0.0f;
            s = su - a * y;
            if (lane == 0) Ksh[wv][t] = (t == 0) ? (y + h0v) : y;
        }
        __syncthreads();
        const int i = lane & 15, g = lane >> 4;
        for (int w = 0; w < NW; ++w) {
            half8 hv;
#pragma unroll
            for (int e = 0; e < 8; ++e) {
                const int t = 32 * w + 15 + i - 8 * g - e;
                hv[e] = (_Float16)((t >= 0 && t < KTAP) ? Ksh[wv][t] : 0.0f);
            }
            *reinterpret_cast<half8*>(afr + ((size_t)(c * NW + w) * 64 + lane) * 8) = hv;
        }
    } else {
        // transpose: x (b,n,c) f32 -> xT (c*4+b, p) f16, zero-padded
        const int bid2 = bid - NAPREP;
        const int px   = bid2 % 133;
        const int cy   = (bid2 / 133) & 7;
        const int bz   = bid2 / (133 * 8);
        const int p0 = px * 64, c0 = cy * 64, t = threadIdx.x;
        const int cl = (t & 15) * 4;
        const int rl = t >> 4;
#pragma unroll
        for (int pass = 0; pass < 4; ++pass) {
            const int pl = rl + 16 * pass;
            const int r  = p0 + pl - PAD0;
            float4 v = {0.0f, 0.0f, 0.0f, 0.0f};
            if (r >= 0 && r < LSEQ)
                v = *reinterpret_cast<const float4*>(x + ((size_t)bz * LSEQ + r) * CH + c0 + cl);
            tile[pl][cl + 0] = (_Float16)v.x;
            tile[pl][cl + 1] = (_Float16)v.y;
            tile[pl][cl + 2] = (_Float16)v.z;
            tile[pl][cl + 3] = (_Float16)v.w;
        }
        __syncthreads();
        const int pl2 = (t & 15) * 4;
#pragma unroll
        for (int pass = 0; pass < 4; ++pass) {
            const int cc = (t >> 4) + 16 * pass;
            half4 hv;
#pragma unroll
            for (int d = 0; d < 4; ++d) hv[d] = tile[pl2 + d][cc];
            *reinterpret_cast<half4*>(xT + ((size_t)((c0 + cc) * NBATCH + bz)) * PADP + p0 + pl2) = hv;
        }
    }
}

// ---------------------------------------------------------------------------
// Kernel 2: FIR as banded-Toeplitz MFMA + gelu, LDS-staged xT (PROVEN R8
// structure, 38.8us) with ONE change: lout aliased onto xs -> LDS 58.9->42KB
// -> 3 blocks/CU (was 2). Plus R12's proven float4 gather-stores.
// Block = 16 ch x 1024 n (4 tiles of 256) x 1 batch. Grid 1024, chgrp-major
// XCD swizzle. Main loop w-outer/tile-inner: A-frag global (L2), B-frag
// ds_read_b128 1:1 MFMA, acc[4][4].
// ---------------------------------------------------------------------------
__global__ __launch_bounds__(256) void fir_mfma(const _Float16* __restrict__ xT,
                                                const _Float16* __restrict__ afr,
                                                float* __restrict__ out) {
    __shared__ __align__(16) char smem[SMEMB];          // xs; lout aliases it
    const int gid     = blockIdx.x;
    const int logical = (gid & 7) * 128 + (gid >> 3);   // bijective (1024%8==0)
    const int chgrp   = logical >> 5;                   // 0..31 (XCD-local slab)
    const int rem     = logical & 31;
    const int bb      = rem >> 3;
    const int tg      = rem & 7;

    // ---- stage x window: 16 groups of 16 threads, one channel each ----
    {
        const int grp = threadIdx.x >> 4;
        const int l16 = threadIdx.x & 15;
        const size_t rowbase = ((size_t)(chgrp * 16 + grp) * NBATCH + bb) * PADP
                             + (size_t)tg * 1024 + 8;   // abs col of xs[.][0]
#pragma unroll
        for (int it = 0; it < 11; ++it) {
            const int chunk = l16 + 16 * it;
            if (chunk < 164) {
                const half8 v = *reinterpret_cast<const half8*>(xT + rowbase + (size_t)chunk * 8);
                *reinterpret_cast<half8*>(smem + (size_t)grp * XROWB + chunk * 16) = v;
            }
        }
    }
    __syncthreads();

    const int wid = threadIdx.x >> 6, lane = threadIdx.x & 63;
    const int j = lane & 15, g = lane >> 4;
    const int c0 = chgrp * 16 + wid * 4;
    const _Float16* af = afr + (size_t)lane * 8;

    f32x4 acc[4][4];
#pragma unroll
    for (int ti = 0; ti < 4; ++ti)
#pragma unroll
        for (int q = 0; q < 4; ++q) acc[ti][q] = (f32x4){0.f, 0.f, 0.f, 0.f};

#pragma unroll
    for (int w = 0; w < NW; ++w) {
        half8 a[4];
#pragma unroll
        for (int q = 0; q < 4; ++q)
            a[q] = *reinterpret_cast<const half8*>(af + (size_t)((c0 + q) * NW + w) * 512);
        const int base = 16 * j + 8 * g - 32 * w + 256;   // xs idx of B-frag, tile 0
#pragma unroll
        for (int ti = 0; ti < 4; ++ti) {
#pragma unroll
            for (int q = 0; q < 4; ++q) {
                const half8 bv = *reinterpret_cast<const half8*>(
                    smem + (size_t)(wid * 4 + q) * XROWB + 2 * (base + 256 * ti));
                acc[ti][q] = __builtin_amdgcn_mfma_f32_16x16x32_f16(a[q], bv, acc[ti][q], 0, 0, 0);
            }
        }
    }

    // ---- epilogue: per tile, gelu -> lout (ALIASES xs) -> float4 stores ----
    const int cq  = threadIdx.x & 3;
    const int nr0 = threadIdx.x >> 2;        // 0..63
#pragma unroll
    for (int ti = 0; ti < 4; ++ti) {
        __syncthreads();                     // xs reads (ti=0) / prev store reads done
#pragma unroll
        for (int q = 0; q < 4; ++q) {
            f32x4 o;
#pragma unroll
            for (int r = 0; r < 4; ++r) {
                const float y  = acc[ti][q][r];
                const float wv = fmaf(y * y, 0.14270963f, 1.5957691f);
                const float e  = __expf(y * wv);
                o[r] = y - y * __builtin_amdgcn_rcpf(e + 1.0f);
            }
            *reinterpret_cast<f32x4*>(smem + (size_t)(wid * 4 + q) * LOWB
                                      + 4 * (16 * j + 4 * g)) = o;
        }
        __syncthreads();
        float* obp = out + ((size_t)bb * LSEQ + tg * 1024 + ti * 256) * CH + chgrp * 16 + 4 * cq;
#pragma unroll
        for (int it = 0; it < 4; ++it) {
            const int n = nr0 + 64 * it;
            f32x4 o;
            o[0] = *reinterpret_cast<const float*>(smem + (size_t)(4 * cq + 0) * LOWB + 4 * n);
            o[1] = *reinterpret_cast<const float*>(smem + (size_t)(4 * cq + 1) * LOWB + 4 * n);
            o[2] = *reinterpret_cast<const float*>(smem + (size_t)(4 * cq + 2) * LOWB + 4 * n);
            o[3] = *reinterpret_cast<const float*>(smem + (size_t)(4 * cq + 3) * LOWB + 4 * n);
            *reinterpret_cast<f32x4*>(obp + (size_t)n * CH) = o;
        }
    }
}

// ======================== FALLBACK (R5, proven 138us) =======================
#define RINGF 32
#define CPBF  256
__global__ __launch_bounds__(ORDER) void rtf_impulse_fb(const float* __restrict__ A,
                                                        const float* __restrict__ B,
                                                        const float* __restrict__ h0,
                                                        float* __restrict__ kt4) {
    const int c = blockIdx.x, lane = threadIdx.x;
    const float a = A[c * ORDER + lane], bc = B[c * ORDER + lane], h0v = h0[0];
    float s = 0.0f;
    for (int t = 0; t < KTAP; ++t) {
        const float s1 = __shfl(s, 0);
        const float bt = (t < ORDER) ? __shfl(bc, t) : 0.0f;
        const float y  = bt + s1;
        float su = __shfl_down(s, 1);
        if (lane == ORDER - 1) su = 0.0f;
        s = su - a * y;
        if (lane == 0) kt4[((size_t)(t >> 2) * CH + c) * 4 + (t & 3)] = (t == 0) ? (y + h0v) : y;
    }
}
__global__ __launch_bounds__(CPBF) void fir_gelu_fb(const float* __restrict__ x,
                                                    const float* __restrict__ kt4,
                                                    float* __restrict__ out) {
    const int h = blockIdx.x;
    const int logical = ((h & 7) << 8) | (h >> 3);
    const int tile = logical & 255, sl = logical >> 8;
    const int cb = sl & 1, b = sl >> 1;
    const int c = cb * CPBF + threadIdx.x;
    const int n0 = tile * RINGF;
    const float* xb = x + (size_t)b * LSEQ * CH + c;
    const float4* kt4v = (const float4*)kt4;
    float acc[RINGF]; float ring[RINGF]; float px[2][8]; float kbuf[2][8];
#pragma unroll
    for (int r = 0; r < RINGF; ++r) acc[r] = 0.0f;
#pragma unroll
    for (int i = 0; i < RINGF; ++i) ring[i] = xb[(size_t)(n0 + i) * CH];
    {
        const float4 ka = kt4v[(size_t)0 * CH + c];
        const float4 kb = kt4v[(size_t)1 * CH + c];
        kbuf[0][0] = ka.x; kbuf[0][1] = ka.y; kbuf[0][2] = ka.z; kbuf[0][3] = ka.w;
        kbuf[0][4] = kb.x; kbuf[0][5] = kb.y; kbuf[0][6] = kb.z; kbuf[0][7] = kb.w;
#pragma unroll
        for (int g2 = 0; g2 < 8; ++g2) {
            const int m = n0 - 1 - g2;
            px[0][g2] = (m >= 0) ? xb[(size_t)m * CH] : 0.0f;
        }
    }
    for (int tb = 0; tb < KTAP; tb += RINGF) {
#pragma unroll
        for (int qq = 0; qq < 4; ++qq) {
            const int cur = qq & 1, nxt = cur ^ 1;
            const int tn = tb + 8 * (qq + 1);
            if (tn < KTAP) {
                const float4 ka = kt4v[(size_t)(tn >> 2) * CH + c];
                const float4 kb = kt4v[(size_t)((tn >> 2) + 1) * CH + c];
                kbuf[nxt][0] = ka.x; kbuf[nxt][1] = ka.y; kbuf[nxt][2] = ka.z; kbuf[nxt][3] = ka.w;
                kbuf[nxt][4] = kb.x; kbuf[nxt][5] = kb.y; kbuf[nxt][6] = kb.z; kbuf[nxt][7] = kb.w;
#pragma unroll
                for (int g2 = 0; g2 < 8; ++g2) {
                    const int m = n0 - tn - 1 - g2;
                    px[nxt][g2] = (m >= 0) ? xb[(size_t)m * CH] : 0.0f;
                }
            }
#pragma unroll
            for (int g2 = 0; g2 < 8; ++g2) {
                const int tq = 8 * qq + g2;
                const float kv = kbuf[cur][g2];
#pragma unroll
                for (int r = 0; r < RINGF; ++r)
                    acc[r] = fmaf(kv, ring[(r - tq) & (RINGF - 1)], acc[r]);
                ring[(RINGF - 1 - tq) & (RINGF - 1)] = px[cur][g2];
            }
        }
    }
    float* ob = out + ((size_t)b * LSEQ + n0) * CH + c;
#pragma unroll
    for (int r = 0; r < RINGF; ++r) {
        const float y = acc[r];
        const float wv = fmaf(y * y, 0.14270963f, 1.5957691f);
        const float e = __expf(y * wv);
        ob[(size_t)r * CH] = y - y * __builtin_amdgcn_rcpf(e + 1.0f);
    }
}

extern "C" void kernel_launch(void* const* d_in, const int* in_sizes, int n_in,
                              void* d_out, int out_size, void* d_ws, size_t ws_size,
                              hipStream_t stream) {
    const float* x  = (const float*)d_in[0];
    const float* A  = (const float*)d_in[1];
    const float* B  = (const float*)d_in[2];
    const float* h0 = (const float*)d_in[3];
    float* out = (float*)d_out;

    if (ws_size >= WS_NEED) {
        _Float16* afr = (_Float16*)d_ws;
        _Float16* xT  = afr + AFRAG_HALFS;
        prep<<<dim3(NAPREP + NXPOSE), dim3(256), 0, stream>>>(A, B, h0, x, afr, xT);
        fir_mfma<<<dim3(1024), dim3(256), 0, stream>>>(xT, afr, out);
    } else {
        float* kt4 = (float*)d_ws;  // 512 KB
        rtf_impulse_fb<<<dim3(CH), dim3(ORDER), 0, stream>>>(A, B, h0, kt4);
        fir_gelu_fb<<<dim3((LSEQ / RINGF) * (CH / CPBF) * NBATCH), dim3(CPBF), 0, stream>>>(x, kt4, out);
    }
}